// Round 18
// baseline (325.589 us; speedup 1.0000x reference)
//
#include <hip/hip_runtime.h>
#include <stdint.h>

// N=16, M=4, D=32, K=256, H=64, W=64 ; P = 262144 pixels
// outputs (concat, read back as f32): sample (P*256), code (P, as float), logit (P*256)
// d_ws: [c2 table: 1024 f32 = 4KB][halves: uint2[2][P] = 4MB]
// R18 = R17 grid + codebook rows via inline-asm s_load into SGPRs (scalar pipe,
// no per-lane register replication). c2 from a global table (kernel 0) so the
// hot loop contains ONLY our lgkm ops (manual s_waitcnt is exact).

#define TINY_F 1.17549435082228750797e-38f
#define LN2F   0.69314718055994530942f
#define MARGIN 2.0e-4f

constexpr int KK   = 256;
constexpr int DD   = 32;
constexpr int HALF = 128;
constexpr int P_TOT = 262144;

typedef float f32x16 __attribute__((ext_vector_type(16)));

// XLA:CPU vectorized log (GenerateVF32Log / Eigen plog), UNFUSED mul+add.
// Bit-exactness validated round 2 (code absmax == 0). Exact path only.
__device__ __forceinline__ float plog_xla(float xin) {
  #pragma clang fp contract(off)
  uint32_t ix = __float_as_uint(xin);
  int e_i = (int)(ix >> 23) - 126;
  float x = __uint_as_float((ix & 0x007FFFFFu) | 0x3F000000u);
  float e = (float)e_i;
  bool lt = x < 0.707106781186547524f;
  float tmp = lt ? x : 0.0f;
  x = x - 1.0f;
  e = e - (lt ? 1.0f : 0.0f);
  x = x + tmp;
  float z  = x * x;
  float x3 = z * x;
  float y  =  7.0376836292e-2f * x + (-1.1514610310e-1f);
  float y1 = -1.2420140846e-1f * x +   1.4249322787e-1f;
  float y2 =  2.0000714765e-1f * x + (-2.4999993993e-1f);
  y  = y  * x +   1.1676998740e-1f;
  y1 = y1 * x + (-1.6668057665e-1f);
  y2 = y2 * x +   3.3333331174e-1f;
  y  = y * x3 + y1;
  y  = y * x3 + y2;
  y  = y * x3;
  y  = y + e * (-2.12194440e-4f);
  x  = x - 0.5f * z;
  x  = x + y;
  x  = x + e * 0.693359375f;
  return x;
}

__device__ __forceinline__ float sumsq_unfused(const float* v) {
  #pragma clang fp contract(off)
  float a = 0.0f;
  #pragma unroll
  for (int d = 0; d < 32; d++) a = a + v[d] * v[d];
  return a;
}

__device__ __forceinline__ void threefry2x32(uint32_t k0, uint32_t k1,
                                             uint32_t x0, uint32_t x1,
                                             uint32_t& o0, uint32_t& o1) {
  uint32_t ks2 = k0 ^ k1 ^ 0x1BD11BDAu;
  x0 += k0; x1 += k1;
#define TF_RND(r) { x0 += x1; x1 = (x1 << (r)) | (x1 >> (32 - (r))); x1 ^= x0; }
  TF_RND(13) TF_RND(15) TF_RND(26) TF_RND(6)
  x0 += k1; x1 += ks2 + 1u;
  TF_RND(17) TF_RND(29) TF_RND(16) TF_RND(24)
  x0 += ks2; x1 += k0 + 2u;
  TF_RND(13) TF_RND(15) TF_RND(26) TF_RND(6)
  x0 += k0; x1 += k1 + 3u;
  TF_RND(17) TF_RND(29) TF_RND(16) TF_RND(24)
  x0 += k1; x1 += ks2 + 4u;
  TF_RND(13) TF_RND(15) TF_RND(26) TF_RND(6)
  x0 += ks2; x1 += k0 + 5u;
#undef TF_RND
  o0 = x0; o1 = x1;
}

// EXACT gumbel (validated R2).
__device__ __forceinline__ float gumbel_from_bits(uint32_t bits) {
  uint32_t mant = bits >> 9;
  float f = __uint_as_float(0x3F800000u | mant) - 1.0f;
  float u = mant ? f : TINY_F;
  float t = -plog_xla(u);
  return -plog_xla(t);
}

// FAST gumbel via v_log_f32 (scan only; certified by margin).
__device__ __forceinline__ float gumbel_fast(uint32_t bits) {
  uint32_t mant = bits >> 9;
  float f = __uint_as_float(0x3F800000u | mant) - 1.0f;
  float u = mant ? f : TINY_F;
  float t = -(__log2f(u) * LN2F);
  return -(__log2f(t) * LN2F);
}

#define TRACK(P, KL, BEST, SEC, THI, I1, I2)                                   \
  if ((P) > BEST) { THI = SEC; SEC = BEST; I2 = I1; BEST = (P); I1 = (KL); }   \
  else if ((P) > SEC) { THI = SEC; SEC = (P); I2 = (KL); }                     \
  else if ((P) > THI) THI = (P);

// exact phi for local row KL (vector loads; rare path, L1-hot)
#define EXACT_PHI(OUT, KL)                                                     \
  {                                                                            \
    const int _kl = (KL);                                                      \
    const float4* _rp = (const float4*)(cbm + (size_t)_kl * DD);               \
    float _in = 0.0f;                                                          \
    _Pragma("unroll")                                                          \
    for (int _j = 0; _j < 8; _j++) {                                           \
      float4 _q = _rp[_j];                                                     \
      _in = __builtin_fmaf(xv[4*_j+0], _q.x, _in);                             \
      _in = __builtin_fmaf(xv[4*_j+1], _q.y, _in);                             \
      _in = __builtin_fmaf(xv[4*_j+2], _q.z, _in);                             \
      _in = __builtin_fmaf(xv[4*_j+3], _q.w, _in);                             \
    }                                                                          \
    float _d = (x2 + c2h[_kl]) - 2.0f * _in;                                   \
    float _L = plog_xla(_d);                                                   \
    uint32_t _v0, _v1;                                                         \
    threefry2x32(0u, 42u, 0u, lbase + (uint32_t)_kl, _v0, _v1);                \
    OUT = gumbel_from_bits(_v0 ^ _v1) + _L;                                    \
  }

// kernel 0: c2 table (1024 floats) into d_ws head. Validated unfused chain.
__global__ __launch_bounds__(256)
void mcq_c2(const float* __restrict__ cb, float* __restrict__ c2tab) {
  const int m = blockIdx.x;            // 4 blocks
  const int k = threadIdx.x;           // 256 threads
  const float4* rp = (const float4*)(cb + ((size_t)m * KK + k) * DD);
  float cr[DD];
  #pragma unroll
  for (int j = 0; j < 8; j++) {
    float4 q = rp[j];
    cr[4*j+0] = q.x; cr[4*j+1] = q.y; cr[4*j+2] = q.z; cr[4*j+3] = q.w;
  }
  c2tab[m * KK + k] = sumsq_unfused(cr);
}

// one k: compute from (CA0,CA1,CC2), prefetch k+1 -> (NB0,NB1,NC2) via s_load
#define KS(KIDX, CA0, CA1, CC2, NB0, NB1, NC2, LOUT)                           \
  {                                                                            \
    const int kl = (KIDX);                                                     \
    const int kn = (kl + 1) & (HALF - 1);                                      \
    const float* nptr = cbm + (size_t)kn * DD;                                 \
    const float* ncp  = c2h + kn;                                              \
    asm volatile("s_load_dwordx16 %0, %3, 0x0\n\t"                             \
                 "s_load_dwordx16 %1, %3, 0x40\n\t"                            \
                 "s_load_dword %2, %4, 0x0"                                    \
                 : "=&s"(NB0), "=&s"(NB1), "=&s"(NC2)                          \
                 : "s"(nptr), "s"(ncp));                                       \
    float inter = 0.0f;                                                        \
    _Pragma("unroll")                                                          \
    for (int d = 0; d < 16; d++)                                               \
      inter = __builtin_fmaf(xv[d], CA0[d], inter);                            \
    _Pragma("unroll")                                                          \
    for (int d = 0; d < 16; d++)                                               \
      inter = __builtin_fmaf(xv[16 + d], CA1[d], inter);                       \
    float dd = (x2 + CC2) - 2.0f * inter;                                      \
    LOUT = __log2f(dd) * LN2F;                                                 \
    uint32_t v0_, v1_;                                                         \
    threefry2x32(0u, 42u, 0u, lbase + (uint32_t)kl, v0_, v1_);                 \
    float p_ = gumbel_fast(v0_ ^ v1_) + LOUT;                                  \
    TRACK(p_, kl, best, sec, thi, bi1, bi2)                                    \
    asm volatile("s_waitcnt lgkmcnt(0)"                                        \
                 : "+s"(NB0), "+s"(NB1), "+s"(NC2));                           \
  }

__global__ __launch_bounds__(256, 8)
void mcq_main(const float* __restrict__ x, const float* __restrict__ cb,
              const float* __restrict__ c2tab,
              float* __restrict__ logit, uint2* __restrict__ ws) {
  const int t   = threadIdx.x;
  const int bid = blockIdx.x;          // 2048 blocks = (group g, half h)
  const int g   = bid >> 1;
  const int h   = bid & 1;
  const int nm  = g >> 4;
  const int m   = nm & 3;
  const int hw  = ((g & 15) << 8) + t;
  const int gp  = (nm << 12) + hw;     // global pixel

  const float* cbm = cb + (size_t)m * (KK * DD) + (size_t)h * (HALF * DD);
  const float* c2h = c2tab + m * KK + h * HALF;

  // x[d] -> VGPRs (coalesced across threads per d)
  const float* xp = x + ((size_t)(nm * 32)) * 4096 + hw;
  float xv[DD];
  #pragma unroll
  for (int d = 0; d < DD; d++) xv[d] = xp[(size_t)d * 4096];
  const float x2 = sumsq_unfused(xv);

  float* lrow = logit + ((size_t)gp << 8) + h * HALF;
  const uint32_t lbase = ((uint32_t)gp << 8) + (uint32_t)(h * HALF);

  float best = -__builtin_inff(), sec = -__builtin_inff(), thi = -__builtin_inff();
  int bi1 = 0, bi2 = 0;

  // prologue: row 0 + c2[0] into A
  f32x16 A0, A1, B0, B1;
  float cA, cB;
  asm volatile("s_load_dwordx16 %0, %3, 0x0\n\t"
               "s_load_dwordx16 %1, %3, 0x40\n\t"
               "s_load_dword %2, %4, 0x0"
               : "=&s"(A0), "=&s"(A1), "=&s"(cA)
               : "s"(cbm), "s"(c2h));
  asm volatile("s_waitcnt lgkmcnt(0)" : "+s"(A0), "+s"(A1), "+s"(cA));

  #pragma unroll 1
  for (int kc = 0; kc < HALF; kc += 8) {
    float L0, L1, L2, L3, L4, L5, L6, L7;   // named regs only
    KS(kc + 0, A0, A1, cA, B0, B1, cB, L0)
    KS(kc + 1, B0, B1, cB, A0, A1, cA, L1)
    KS(kc + 2, A0, A1, cA, B0, B1, cB, L2)
    KS(kc + 3, B0, B1, cB, A0, A1, cA, L3)
    KS(kc + 4, A0, A1, cA, B0, B1, cB, L4)
    KS(kc + 5, B0, B1, cB, A0, A1, cA, L5)
    KS(kc + 6, A0, A1, cA, B0, B1, cB, L6)
    KS(kc + 7, B0, B1, cB, A0, A1, cA, L7)   // leaves next row in A
    float4* dst = (float4*)(lrow + kc);      // 32B bursts
    dst[0] = make_float4(L0, L1, L2, L3);
    dst[1] = make_float4(L4, L5, L6, L7);
  }

  // resolve half-winner with exact phi (validated R10 logic)
  int wbl; float fw;
  if (best - sec > MARGIN) {
    wbl = bi1;
    EXACT_PHI(fw, wbl)
  } else if (best - thi > MARGIN) {
    int ka = bi1 < bi2 ? bi1 : bi2;
    int kb = bi1 < bi2 ? bi2 : bi1;
    float fa, fb;
    EXACT_PHI(fa, ka)
    EXACT_PHI(fb, kb)
    if (fb > fa) { wbl = kb; fw = fb; } else { wbl = ka; fw = fa; }
  } else {
    float bb = -__builtin_inff(); int wbb = 0;
    for (int kl = 0; kl < HALF; kl++) {
      float ph;
      EXACT_PHI(ph, kl)
      if (ph > bb) { bb = ph; wbb = kl; }
    }
    wbl = wbb; fw = bb;
  }

  ws[(h << 18) + gp] = make_uint2(__float_as_uint(fw), (uint32_t)(wbl + h * HALF));
}

__global__ __launch_bounds__(256)
void mcq_combine(const uint2* __restrict__ ws, float* __restrict__ sample,
                 float* __restrict__ code) {
  __shared__ int s_wb[256];
  const int t = threadIdx.x;
  const int b = blockIdx.x;          // 1024 blocks x 256 pixels
  const int gp = (b << 8) + t;

  uint2 a = ws[gp];
  uint2 c = ws[P_TOT + gp];
  float fa = __uint_as_float(a.x);
  float fc = __uint_as_float(c.x);
  // exact compare; tie -> half 0 (smaller k, first occurrence)
  int win = (fc > fa) ? (int)c.y : (int)a.y;

  code[gp] = (float)win;
  s_wb[t] = win;
  __syncthreads();

  const int lane = t & 63, wv = t >> 6;
  const int pbase = b << 8;
  const int k0 = lane << 2;
  for (int r = wv * 64; r < (wv + 1) * 64; r++) {
    const int w = s_wb[r];
    float4 v;
    v.x = (w == k0 + 0) ? 1.0f : 0.0f;
    v.y = (w == k0 + 1) ? 1.0f : 0.0f;
    v.z = (w == k0 + 2) ? 1.0f : 0.0f;
    v.w = (w == k0 + 3) ? 1.0f : 0.0f;
    ((float4*)(sample + (((size_t)(pbase + r)) << 8)))[lane] = v;
  }
}

extern "C" void kernel_launch(void* const* d_in, const int* in_sizes, int n_in,
                              void* d_out, int out_size, void* d_ws, size_t ws_size,
                              hipStream_t stream) {
  const float* x  = (const float*)d_in[0];
  const float* cb = (const float*)d_in[1];

  float* out_f  = (float*)d_out;
  float* sample = out_f;                       // 67108864
  float* code   = out_f + 67108864;            // 262144 (as float)
  float* logit  = out_f + 67108864 + 262144;   // 67108864

  float* c2tab  = (float*)d_ws;                         // 4 KB
  uint2* halves = (uint2*)((char*)d_ws + 4096);         // 4 MB

  mcq_c2<<<4, 256, 0, stream>>>(cb, c2tab);
  mcq_main<<<2048, 256, 0, stream>>>(x, cb, c2tab, logit, halves);
  mcq_combine<<<1024, 256, 0, stream>>>(halves, sample, code);
}

// Round 19
// 300.131 us; speedup vs baseline: 1.0848x; 1.0848x over previous
//
#include <hip/hip_runtime.h>
#include <stdint.h>

// N=16, M=4, D=32, K=256, H=64, W=64 ; P = 262144 pixels
// outputs (concat, read back as f32): sample (P*256), code (P, as float), logit (P*256)
// d_ws: c2 table (1024 f32)
// R19: TWO kernels. mcq_full: 2048 blocks x 128 threads (thread = pixel,
// FULL 256-k scan) -> 16 WGs/CU x 2 waves = 32 waves/CU (100% occ) with
// VGPR=64. No k-split => no ws halves, no combine kernel; the 268 MB one-hot
// write overlaps main's compute. Rows via wave-uniform GLOBAL loads (R17,
// validated); c2 via precompute table (R18, validated). Arithmetic bit-frozen.

#define TINY_F 1.17549435082228750797e-38f
#define LN2F   0.69314718055994530942f
#define MARGIN 2.0e-4f

constexpr int KK = 256;
constexpr int DD = 32;

// XLA:CPU vectorized log (GenerateVF32Log / Eigen plog), UNFUSED mul+add.
// Bit-exactness validated round 2 (code absmax == 0). Exact path only.
__device__ __forceinline__ float plog_xla(float xin) {
  #pragma clang fp contract(off)
  uint32_t ix = __float_as_uint(xin);
  int e_i = (int)(ix >> 23) - 126;
  float x = __uint_as_float((ix & 0x007FFFFFu) | 0x3F000000u);
  float e = (float)e_i;
  bool lt = x < 0.707106781186547524f;
  float tmp = lt ? x : 0.0f;
  x = x - 1.0f;
  e = e - (lt ? 1.0f : 0.0f);
  x = x + tmp;
  float z  = x * x;
  float x3 = z * x;
  float y  =  7.0376836292e-2f * x + (-1.1514610310e-1f);
  float y1 = -1.2420140846e-1f * x +   1.4249322787e-1f;
  float y2 =  2.0000714765e-1f * x + (-2.4999993993e-1f);
  y  = y  * x +   1.1676998740e-1f;
  y1 = y1 * x + (-1.6668057665e-1f);
  y2 = y2 * x +   3.3333331174e-1f;
  y  = y * x3 + y1;
  y  = y * x3 + y2;
  y  = y * x3;
  y  = y + e * (-2.12194440e-4f);
  x  = x - 0.5f * z;
  x  = x + y;
  x  = x + e * 0.693359375f;
  return x;
}

__device__ __forceinline__ float sumsq_unfused(const float* v) {
  #pragma clang fp contract(off)
  float a = 0.0f;
  #pragma unroll
  for (int d = 0; d < 32; d++) a = a + v[d] * v[d];
  return a;
}

__device__ __forceinline__ void threefry2x32(uint32_t k0, uint32_t k1,
                                             uint32_t x0, uint32_t x1,
                                             uint32_t& o0, uint32_t& o1) {
  uint32_t ks2 = k0 ^ k1 ^ 0x1BD11BDAu;
  x0 += k0; x1 += k1;
#define TF_RND(r) { x0 += x1; x1 = (x1 << (r)) | (x1 >> (32 - (r))); x1 ^= x0; }
  TF_RND(13) TF_RND(15) TF_RND(26) TF_RND(6)
  x0 += k1; x1 += ks2 + 1u;
  TF_RND(17) TF_RND(29) TF_RND(16) TF_RND(24)
  x0 += ks2; x1 += k0 + 2u;
  TF_RND(13) TF_RND(15) TF_RND(26) TF_RND(6)
  x0 += k0; x1 += k1 + 3u;
  TF_RND(17) TF_RND(29) TF_RND(16) TF_RND(24)
  x0 += k1; x1 += ks2 + 4u;
  TF_RND(13) TF_RND(15) TF_RND(26) TF_RND(6)
  x0 += ks2; x1 += k0 + 5u;
#undef TF_RND
  o0 = x0; o1 = x1;
}

// EXACT gumbel (validated R2). Resolve path only.
__device__ __forceinline__ float gumbel_from_bits(uint32_t bits) {
  uint32_t mant = bits >> 9;
  float f = __uint_as_float(0x3F800000u | mant) - 1.0f;
  float u = mant ? f : TINY_F;
  float t = -plog_xla(u);
  return -plog_xla(t);
}

// FAST gumbel via v_log_f32 (scan only; certified by margin).
__device__ __forceinline__ float gumbel_fast(uint32_t bits) {
  uint32_t mant = bits >> 9;
  float f = __uint_as_float(0x3F800000u | mant) - 1.0f;
  float u = mant ? f : TINY_F;
  float t = -(__log2f(u) * LN2F);
  return -(__log2f(t) * LN2F);
}

#define TRACK(P, KL, BEST, SEC, THI, I1, I2)                                   \
  if ((P) > BEST) { THI = SEC; SEC = BEST; I2 = I1; BEST = (P); I1 = (KL); }   \
  else if ((P) > SEC) { THI = SEC; SEC = (P); I2 = (KL); }                     \
  else if ((P) > THI) THI = (P);

// exact phi for row KI (per-lane addr; rare path, L1-hot)
#define EXACT_PHI(OUT, KI)                                                     \
  {                                                                            \
    const int _ki = (KI);                                                      \
    const float4* _rp = (const float4*)(cbm + (size_t)_ki * DD);               \
    float _in = 0.0f;                                                          \
    _Pragma("unroll")                                                          \
    for (int _j = 0; _j < 8; _j++) {                                           \
      float4 _q = _rp[_j];                                                     \
      _in = __builtin_fmaf(xv[4*_j+0], _q.x, _in);                             \
      _in = __builtin_fmaf(xv[4*_j+1], _q.y, _in);                             \
      _in = __builtin_fmaf(xv[4*_j+2], _q.z, _in);                             \
      _in = __builtin_fmaf(xv[4*_j+3], _q.w, _in);                             \
    }                                                                          \
    float _d = (x2 + c2m[_ki]) - 2.0f * _in;                                   \
    float _L = plog_xla(_d);                                                   \
    uint32_t _v0, _v1;                                                         \
    threefry2x32(0u, 42u, 0u, lbase | (uint32_t)_ki, _v0, _v1);                \
    OUT = gumbel_from_bits(_v0 ^ _v1) + _L;                                    \
  }

// two k per expansion: rows from GLOBAL, wave-uniform addr (one line/wave)
#define K2(KOFF, LA, LB)                                                       \
  {                                                                            \
    const int k0 = kc + (KOFF);                                                \
    const float2 c2p = *(const float2*)(c2m + k0);                             \
    const float4* rA = (const float4*)(cbm + (size_t)k0 * DD);                 \
    const float4* rB = rA + 8;                                                 \
    float i0 = 0.0f, i1 = 0.0f;                                                \
    _Pragma("unroll")                                                          \
    for (int j = 0; j < 8; j++) {                                              \
      float4 qa = rA[j], qb = rB[j];                                           \
      i0 = __builtin_fmaf(xv[4*j+0], qa.x, i0);                                \
      i1 = __builtin_fmaf(xv[4*j+0], qb.x, i1);                                \
      i0 = __builtin_fmaf(xv[4*j+1], qa.y, i0);                                \
      i1 = __builtin_fmaf(xv[4*j+1], qb.y, i1);                                \
      i0 = __builtin_fmaf(xv[4*j+2], qa.z, i0);                                \
      i1 = __builtin_fmaf(xv[4*j+2], qb.z, i1);                                \
      i0 = __builtin_fmaf(xv[4*j+3], qa.w, i0);                                \
      i1 = __builtin_fmaf(xv[4*j+3], qb.w, i1);                                \
    }                                                                          \
    float d0 = (x2 + c2p.x) - 2.0f * i0;                                       \
    float d1 = (x2 + c2p.y) - 2.0f * i1;                                       \
    LA = __log2f(d0) * LN2F;                                                   \
    LB = __log2f(d1) * LN2F;                                                   \
    uint32_t a0, a1, b0, b1;                                                   \
    threefry2x32(0u, 42u, 0u, lbase | (uint32_t)k0,       a0, a1);             \
    threefry2x32(0u, 42u, 0u, lbase | (uint32_t)(k0 + 1), b0, b1);             \
    float pA = gumbel_fast(a0 ^ a1) + LA;                                      \
    float pB = gumbel_fast(b0 ^ b1) + LB;                                      \
    TRACK(pA, k0,     best, sec, thi, bi1, bi2)                                \
    TRACK(pB, k0 + 1, best, sec, thi, bi1, bi2)                                \
  }

// kernel 0: c2 table (1024 floats) into d_ws. Validated unfused chain.
__global__ __launch_bounds__(256)
void mcq_c2(const float* __restrict__ cb, float* __restrict__ c2tab) {
  const int m = blockIdx.x;            // 4 blocks
  const int k = threadIdx.x;           // 256 threads
  const float4* rp = (const float4*)(cb + ((size_t)m * KK + k) * DD);
  float cr[DD];
  #pragma unroll
  for (int j = 0; j < 8; j++) {
    float4 q = rp[j];
    cr[4*j+0] = q.x; cr[4*j+1] = q.y; cr[4*j+2] = q.z; cr[4*j+3] = q.w;
  }
  c2tab[m * KK + k] = sumsq_unfused(cr);
}

__global__ __launch_bounds__(128, 8)
void mcq_full(const float* __restrict__ x, const float* __restrict__ cb,
              const float* __restrict__ c2tab, float* __restrict__ sample,
              float* __restrict__ code, float* __restrict__ logit) {
  __shared__ int s_wb[128];

  const int t     = threadIdx.x;             // 128 threads = 2 waves
  const int pbase = blockIdx.x << 7;         // 2048 blocks x 128 px
  const int nm    = pbase >> 12;             // uniform (128 | 4096)
  const int m     = nm & 3;
  const int hw    = (pbase & 4095) + t;
  const int gp    = pbase + t;

  const float* cbm = cb + (size_t)m * (KK * DD);
  const float* c2m = c2tab + m * KK;

  // x[d] -> VGPRs (coalesced across threads per d)
  const float* xp = x + ((size_t)(nm * 32)) * 4096 + hw;
  float xv[DD];
  #pragma unroll
  for (int d = 0; d < DD; d++) xv[d] = xp[(size_t)d * 4096];
  const float x2 = sumsq_unfused(xv);

  float* lrow = logit + ((size_t)gp << 8);
  const uint32_t lbase = (uint32_t)gp << 8;

  float best = -__builtin_inff(), sec = -__builtin_inff(), thi = -__builtin_inff();
  int bi1 = 0, bi2 = 0;

  #pragma unroll 1
  for (int kc = 0; kc < KK; kc += 16) {
    float L0,L1,L2,L3,L4,L5,L6,L7,L8,L9,L10,L11,L12,L13,L14,L15;  // named only
    K2(0,  L0,  L1)
    K2(2,  L2,  L3)
    K2(4,  L4,  L5)
    K2(6,  L6,  L7)
    K2(8,  L8,  L9)
    K2(10, L10, L11)
    K2(12, L12, L13)
    K2(14, L14, L15)
    // 64B full-line burst (lrow 1KB-aligned, kc multiple of 16)
    float4* dst = (float4*)(lrow + kc);
    dst[0] = make_float4(L0,  L1,  L2,  L3);
    dst[1] = make_float4(L4,  L5,  L6,  L7);
    dst[2] = make_float4(L8,  L9,  L10, L11);
    dst[3] = make_float4(L12, L13, L14, L15);
  }

  // resolve winner (validated top-3 margin logic; exact chains)
  int w;
  if (best - sec > MARGIN) {
    w = bi1;
  } else if (best - thi > MARGIN) {
    int ka = bi1 < bi2 ? bi1 : bi2;
    int kb = bi1 < bi2 ? bi2 : bi1;
    float fa, fb;
    EXACT_PHI(fa, ka)
    EXACT_PHI(fb, kb)
    w = (fb > fa) ? kb : ka;                 // tie -> smaller k (first occurrence)
  } else {
    // ultra-rare: full exact rescan
    float bb = -__builtin_inff(); int wbb = 0;
    for (int k2i = 0; k2i < KK; k2i++) {
      float ph;
      EXACT_PHI(ph, k2i)
      if (ph > bb) { bb = ph; wbb = k2i; }
    }
    w = wbb;
  }

  code[gp] = (float)w;
  s_wb[t] = w;
  __syncthreads();

  // cooperative one-hot sample: each wave-instr writes 1KB contiguous line
  const int lane = t & 63, wv = t >> 6;      // wv in {0,1}
  const int k0 = lane << 2;
  for (int r = wv * 64; r < (wv + 1) * 64; r++) {
    const int wr = s_wb[r];
    float4 v;
    v.x = (wr == k0 + 0) ? 1.0f : 0.0f;
    v.y = (wr == k0 + 1) ? 1.0f : 0.0f;
    v.z = (wr == k0 + 2) ? 1.0f : 0.0f;
    v.w = (wr == k0 + 3) ? 1.0f : 0.0f;
    ((float4*)(sample + (((size_t)(pbase + r)) << 8)))[lane] = v;
  }
}

extern "C" void kernel_launch(void* const* d_in, const int* in_sizes, int n_in,
                              void* d_out, int out_size, void* d_ws, size_t ws_size,
                              hipStream_t stream) {
  const float* x  = (const float*)d_in[0];
  const float* cb = (const float*)d_in[1];

  float* out_f  = (float*)d_out;
  float* sample = out_f;                       // 67108864
  float* code   = out_f + 67108864;            // 262144 (as float)
  float* logit  = out_f + 67108864 + 262144;   // 67108864

  float* c2tab  = (float*)d_ws;                // 4 KB

  mcq_c2<<<4, 256, 0, stream>>>(cb, c2tab);
  mcq_full<<<2048, 128, 0, stream>>>(x, cb, c2tab, sample, code, logit);
}

// Round 20
// 224.692 us; speedup vs baseline: 1.4490x; 1.3357x over previous
//
#include <hip/hip_runtime.h>
#include <hip/hip_bf16.h>
#include <stdint.h>

// N=16, M=4, D=32, K=256, H=64, W=64 ; P = 262144 pixels
// outputs (concat, read back as f32): sample (P*256), code (P, as float), logit (P*256)
// d_ws: [c2tab 4KB][cbh 64KB][cbl 64KB]
// R20: MFMA inter. Block = 256 thr (4 waves) x 64 px; wave = 16 px x 256 k.
// 3-pass bf16 hi/lo MFMA (16x16x32) computes inter; threefry/gumbel/margin
// certification unchanged (validated); exact resolve reloads fp32 (validated
// chains). MARGIN 4e-4 absorbs MFMA dist error (<=1e-4 in phi).

#define TINY_F 1.17549435082228750797e-38f
#define LN2F   0.69314718055994530942f
#define MARGIN 4.0e-4f

constexpr int KK = 256;
constexpr int DD = 32;

typedef __attribute__((ext_vector_type(8))) short bf16x8;
typedef __attribute__((ext_vector_type(4))) float f32x4;

// XLA:CPU vectorized log (validated R2, code absmax == 0). Exact path only.
__device__ __forceinline__ float plog_xla(float xin) {
  #pragma clang fp contract(off)
  uint32_t ix = __float_as_uint(xin);
  int e_i = (int)(ix >> 23) - 126;
  float x = __uint_as_float((ix & 0x007FFFFFu) | 0x3F000000u);
  float e = (float)e_i;
  bool lt = x < 0.707106781186547524f;
  float tmp = lt ? x : 0.0f;
  x = x - 1.0f;
  e = e - (lt ? 1.0f : 0.0f);
  x = x + tmp;
  float z  = x * x;
  float x3 = z * x;
  float y  =  7.0376836292e-2f * x + (-1.1514610310e-1f);
  float y1 = -1.2420140846e-1f * x +   1.4249322787e-1f;
  float y2 =  2.0000714765e-1f * x + (-2.4999993993e-1f);
  y  = y  * x +   1.1676998740e-1f;
  y1 = y1 * x + (-1.6668057665e-1f);
  y2 = y2 * x +   3.3333331174e-1f;
  y  = y * x3 + y1;
  y  = y * x3 + y2;
  y  = y * x3;
  y  = y + e * (-2.12194440e-4f);
  x  = x - 0.5f * z;
  x  = x + y;
  x  = x + e * 0.693359375f;
  return x;
}

__device__ __forceinline__ float sumsq_unfused(const float* v) {
  #pragma clang fp contract(off)
  float a = 0.0f;
  #pragma unroll
  for (int d = 0; d < 32; d++) a = a + v[d] * v[d];
  return a;
}

__device__ __forceinline__ void threefry2x32(uint32_t k0, uint32_t k1,
                                             uint32_t x0, uint32_t x1,
                                             uint32_t& o0, uint32_t& o1) {
  uint32_t ks2 = k0 ^ k1 ^ 0x1BD11BDAu;
  x0 += k0; x1 += k1;
#define TF_RND(r) { x0 += x1; x1 = (x1 << (r)) | (x1 >> (32 - (r))); x1 ^= x0; }
  TF_RND(13) TF_RND(15) TF_RND(26) TF_RND(6)
  x0 += k1; x1 += ks2 + 1u;
  TF_RND(17) TF_RND(29) TF_RND(16) TF_RND(24)
  x0 += ks2; x1 += k0 + 2u;
  TF_RND(13) TF_RND(15) TF_RND(26) TF_RND(6)
  x0 += k0; x1 += k1 + 3u;
  TF_RND(17) TF_RND(29) TF_RND(16) TF_RND(24)
  x0 += k1; x1 += ks2 + 4u;
  TF_RND(13) TF_RND(15) TF_RND(26) TF_RND(6)
  x0 += ks2; x1 += k0 + 5u;
#undef TF_RND
  o0 = x0; o1 = x1;
}

// EXACT gumbel (validated R2). Resolve path only.
__device__ __forceinline__ float gumbel_from_bits(uint32_t bits) {
  uint32_t mant = bits >> 9;
  float f = __uint_as_float(0x3F800000u | mant) - 1.0f;
  float u = mant ? f : TINY_F;
  float t = -plog_xla(u);
  return -plog_xla(t);
}

// FAST gumbel via v_log_f32 (scan only; certified by margin).
__device__ __forceinline__ float gumbel_fast(uint32_t bits) {
  uint32_t mant = bits >> 9;
  float f = __uint_as_float(0x3F800000u | mant) - 1.0f;
  float u = mant ? f : TINY_F;
  float t = -(__log2f(u) * LN2F);
  return -(__log2f(t) * LN2F);
}

__device__ __forceinline__ short bf16_rn_bits(float v) {
  __hip_bfloat16 h = __float2bfloat16(v);
  return *reinterpret_cast<short*>(&h);
}
__device__ __forceinline__ float bf16_to_f(short s) {
  __hip_bfloat16 h = *reinterpret_cast<__hip_bfloat16*>(&s);
  return __bfloat162float(h);
}

#define TRACK(P, KL, BEST, SEC, THI, I1, I2)                                   \
  if ((P) > BEST) { THI = SEC; SEC = BEST; I2 = I1; BEST = (P); I1 = (KL); }   \
  else if ((P) > SEC) { THI = SEC; SEC = (P); I2 = (KL); }                     \
  else if ((P) > THI) THI = (P);

// exact phi, reloading x fresh (validated fused ascending chain + plog gumbel)
#define EXACT_PHI_R(OUT, KI)                                                   \
  {                                                                            \
    const int _ki = (KI);                                                      \
    const float* _rp = cbm + (size_t)_ki * DD;                                 \
    float _in = 0.0f;                                                          \
    _Pragma("unroll 1")                                                        \
    for (int _j = 0; _j < 8; _j++) {                                           \
      float4 _q = *(const float4*)(_rp + (_j << 2));                           \
      _in = __builtin_fmaf(xb[(size_t)((_j<<2)+0)*4096 + hw], _q.x, _in);      \
      _in = __builtin_fmaf(xb[(size_t)((_j<<2)+1)*4096 + hw], _q.y, _in);      \
      _in = __builtin_fmaf(xb[(size_t)((_j<<2)+2)*4096 + hw], _q.z, _in);      \
      _in = __builtin_fmaf(xb[(size_t)((_j<<2)+3)*4096 + hw], _q.w, _in);      \
    }                                                                          \
    float _d = (x2e + c2m[_ki]) - 2.0f * _in;                                  \
    float _L = plog_xla(_d);                                                   \
    uint32_t _v0, _v1;                                                         \
    threefry2x32(0u, 42u, 0u, lbase | (uint32_t)_ki, _v0, _v1);                \
    OUT = gumbel_from_bits(_v0 ^ _v1) + _L;                                    \
  }

// kernel 0: exact c2 table (validated unfused chain)
__global__ __launch_bounds__(256)
void mcq_c2(const float* __restrict__ cb, float* __restrict__ c2tab) {
  const int m = blockIdx.x;            // 4
  const int k = threadIdx.x;           // 256
  const float4* rp = (const float4*)(cb + ((size_t)m * KK + k) * DD);
  float cr[DD];
  #pragma unroll
  for (int j = 0; j < 8; j++) {
    float4 q = rp[j];
    cr[4*j+0] = q.x; cr[4*j+1] = q.y; cr[4*j+2] = q.z; cr[4*j+3] = q.w;
  }
  c2tab[m * KK + k] = sumsq_unfused(cr);
}

// kernel 1: codebook -> bf16 hi/lo tables
__global__ __launch_bounds__(256)
void mcq_cvt(const float* __restrict__ cb, short* __restrict__ cbh,
             short* __restrict__ cbl) {
  const int m = blockIdx.x;            // 4
  const int k = threadIdx.x;           // 256
  const float* row = cb + ((size_t)m * KK + k) * DD;
  short* hrow = cbh + ((size_t)m * KK + k) * DD;
  short* lrow = cbl + ((size_t)m * KK + k) * DD;
  #pragma unroll
  for (int d = 0; d < DD; d++) {
    float v = row[d];
    short hb = bf16_rn_bits(v);
    float hf = bf16_to_f(hb);
    short lb = bf16_rn_bits(v - hf);
    hrow[d] = hb; lrow[d] = lb;
  }
}

__global__ __launch_bounds__(256, 4)
void mcq_mfma(const float* __restrict__ x, const float* __restrict__ cb,
              const float* __restrict__ c2tab, const short* __restrict__ cbh,
              const short* __restrict__ cbl, float* __restrict__ sample,
              float* __restrict__ code, float* __restrict__ logit) {
  __shared__ int s_wb[64];

  const int t   = threadIdx.x;
  const int l   = t & 63, wvw = t >> 6;      // lane, wave
  const int grp = l >> 4;                    // 0..3
  const int pbase = blockIdx.x << 6;         // 4096 blocks x 64 px
  const int nm  = pbase >> 12;               // uniform (64 | 4096)
  const int m   = nm & 3;
  const int pxl = (wvw << 4) + (l & 15);     // 0..63
  const int gp  = pbase + pxl;
  const int hw  = (pbase & 4095) + pxl;

  const float* cbm = cb + (size_t)m * (KK * DD);
  const float* c2m = c2tab + m * KK;
  const short* chm = cbh + (size_t)m * (KK * DD);
  const short* clm = cbl + (size_t)m * (KK * DD);
  const float* xb  = x + (size_t)nm * 131072;

  // B-frag (x) hi/lo + fast x2 (fast path only; exact x2 recomputed on resolve)
  bf16x8 bh, bl;
  float x2p = 0.0f;
  #pragma unroll
  for (int j = 0; j < 8; j++) {
    const int d = (grp << 3) + j;
    float v = xb[(size_t)d * 4096 + hw];
    short hbits = bf16_rn_bits(v);
    float hf = bf16_to_f(hbits);
    short lbits = bf16_rn_bits(v - hf);
    bh[j] = hbits; bl[j] = lbits;
    x2p = __builtin_fmaf(v, v, x2p);
  }
  x2p += __shfl_xor(x2p, 16, 64);
  x2p += __shfl_xor(x2p, 32, 64);
  const float x2f = x2p;

  float* lrowg = logit + ((size_t)gp << 8) + (grp << 2);
  const uint32_t lbase = (uint32_t)gp << 8;

  float best = -__builtin_inff(), sec = -__builtin_inff(), thi = -__builtin_inff();
  int bi1 = 0, bi2 = 0;

  #pragma unroll 1
  for (int kt = 0; kt < 16; kt++) {
    const int krow = (kt << 4) + (l & 15);
    const bf16x8 ah = *(const bf16x8*)(chm + (size_t)krow * DD + (grp << 3));
    const bf16x8 al = *(const bf16x8*)(clm + (size_t)krow * DD + (grp << 3));
    f32x4 acc = {0.0f, 0.0f, 0.0f, 0.0f};
    acc = __builtin_amdgcn_mfma_f32_16x16x32_bf16(al, bh, acc, 0, 0, 0);
    acc = __builtin_amdgcn_mfma_f32_16x16x32_bf16(ah, bl, acc, 0, 0, 0);
    acc = __builtin_amdgcn_mfma_f32_16x16x32_bf16(ah, bh, acc, 0, 0, 0);
    const float4 c2q = *(const float4*)(c2m + (kt << 4) + (grp << 2));
    const int kb = (kt << 4) + (grp << 2);

    float L0, L1, L2, L3;
#define ELEM(R, C2V, LV)                                                       \
    {                                                                          \
      float dist = (x2f + (C2V)) - 2.0f * acc[R];                              \
      LV = __log2f(dist) * LN2F;                                               \
      uint32_t v0_, v1_;                                                       \
      threefry2x32(0u, 42u, 0u, lbase | (uint32_t)(kb + (R)), v0_, v1_);       \
      float p_ = gumbel_fast(v0_ ^ v1_) + LV;                                  \
      const int kk_ = kb + (R);                                                \
      TRACK(p_, kk_, best, sec, thi, bi1, bi2)                                 \
    }
    ELEM(0, c2q.x, L0)
    ELEM(1, c2q.y, L1)
    ELEM(2, c2q.z, L2)
    ELEM(3, c2q.w, L3)
#undef ELEM
    *(float4*)(lrowg + (kt << 4)) = make_float4(L0, L1, L2, L3);
  }

  // merge top-3 across the 4 lanes sharing this px (first-occurrence ties)
#define MERGE(OFF)                                                             \
  {                                                                            \
    float ob = __shfl_xor(best, OFF, 64);                                      \
    float os = __shfl_xor(sec,  OFF, 64);                                      \
    float ot = __shfl_xor(thi,  OFF, 64);                                      \
    int  oi1 = __shfl_xor(bi1,  OFF, 64);                                      \
    int  oi2 = __shfl_xor(bi2,  OFF, 64);                                      \
    bool take = (ob > best) || (ob == best && oi1 < bi1);                      \
    float wb = take ? ob : best, ws2 = take ? os : sec, wt = take ? ot : thi;  \
    int  wi1 = take ? oi1 : bi1, wi2 = take ? oi2 : bi2;                       \
    float lb = take ? best : ob, ls = take ? sec : os;                         \
    int  li1 = take ? bi1 : oi1;                                               \
    bool s2 = (ws2 > lb) || (ws2 == lb && wi2 < li1);                          \
    best = wb; bi1 = wi1;                                                      \
    if (s2) { sec = ws2; bi2 = wi2; thi = fmaxf(wt, lb); }                     \
    else    { sec = lb;  bi2 = li1; thi = fmaxf(ws2, ls); }                    \
  }
  MERGE(16)
  MERGE(32)
#undef MERGE

  if (l < 16) {
    int w;
    if (best - sec > MARGIN) {
      w = bi1;
    } else {
      // exact x2 (validated unfused chain), fresh loads
      float x2e;
      {
        #pragma clang fp contract(off)
        float a = 0.0f;
        #pragma unroll 1
        for (int d = 0; d < DD; d++) {
          float v = xb[(size_t)d * 4096 + hw];
          a = a + v * v;
        }
        x2e = a;
      }
      if (best - thi > MARGIN) {
        int ka = bi1 < bi2 ? bi1 : bi2;
        int kb2 = bi1 < bi2 ? bi2 : bi1;
        float fa, fb;
        EXACT_PHI_R(fa, ka)
        EXACT_PHI_R(fb, kb2)
        w = (fb > fa) ? kb2 : ka;      // tie -> smaller k (first occurrence)
      } else {
        float bb = -__builtin_inff(); int wbb = 0;
        #pragma unroll 1
        for (int k2i = 0; k2i < KK; k2i++) {
          float ph;
          EXACT_PHI_R(ph, k2i)
          if (ph > bb) { bb = ph; wbb = k2i; }
        }
        w = wbb;
      }
    }
    code[gp] = (float)w;
    s_wb[pxl] = w;
  }
  __syncthreads();

  // cooperative one-hot sample: wave wvw writes rows [wvw*16, wvw*16+16)
  const int k0 = l << 2;
  for (int r = wvw * 16; r < wvw * 16 + 16; r++) {
    const int wr = s_wb[r];
    float4 v;
    v.x = (wr == k0 + 0) ? 1.0f : 0.0f;
    v.y = (wr == k0 + 1) ? 1.0f : 0.0f;
    v.z = (wr == k0 + 2) ? 1.0f : 0.0f;
    v.w = (wr == k0 + 3) ? 1.0f : 0.0f;
    ((float4*)(sample + (((size_t)(pbase + r)) << 8)))[l] = v;
  }
}

extern "C" void kernel_launch(void* const* d_in, const int* in_sizes, int n_in,
                              void* d_out, int out_size, void* d_ws, size_t ws_size,
                              hipStream_t stream) {
  const float* x  = (const float*)d_in[0];
  const float* cb = (const float*)d_in[1];

  float* out_f  = (float*)d_out;
  float* sample = out_f;                       // 67108864
  float* code   = out_f + 67108864;            // 262144 (as float)
  float* logit  = out_f + 67108864 + 262144;   // 67108864

  float* c2tab  = (float*)d_ws;                          // 4 KB
  short* cbh    = (short*)((char*)d_ws + 4096);          // 64 KB
  short* cbl    = (short*)((char*)d_ws + 4096 + 65536);  // 64 KB

  mcq_c2<<<4, 256, 0, stream>>>(cb, c2tab);
  mcq_cvt<<<4, 256, 0, stream>>>(cb, cbh, cbl);
  mcq_mfma<<<4096, 256, 0, stream>>>(x, cb, c2tab, cbh, cbl, sample, code, logit);
}

// Round 21
// 220.354 us; speedup vs baseline: 1.4776x; 1.0197x over previous
//
#include <hip/hip_runtime.h>
#include <hip/hip_bf16.h>
#include <stdint.h>

// N=16, M=4, D=32, K=256, H=64, W=64 ; P = 262144 pixels
// outputs (concat, read back as f32): sample (P*256), code (P, as float), logit (P*256)
// d_ws: [c2tab 4KB][cbh 64KB][cbl 64KB]
// R21 = R20 (MFMA inter, validated) + launch_bounds(256,8) to force the
// 64-VGPR / 32-waves-per-CU tier (threefry dep-chains need TLP), + merged
// prologue (c2+cvt in one kernel). Arithmetic bit-identical to R20.

#define TINY_F 1.17549435082228750797e-38f
#define LN2F   0.69314718055994530942f
#define MARGIN 4.0e-4f

constexpr int KK = 256;
constexpr int DD = 32;

typedef __attribute__((ext_vector_type(8))) short bf16x8;
typedef __attribute__((ext_vector_type(4))) float f32x4;

// XLA:CPU vectorized log (validated R2, code absmax == 0). Exact path only.
__device__ __forceinline__ float plog_xla(float xin) {
  #pragma clang fp contract(off)
  uint32_t ix = __float_as_uint(xin);
  int e_i = (int)(ix >> 23) - 126;
  float x = __uint_as_float((ix & 0x007FFFFFu) | 0x3F000000u);
  float e = (float)e_i;
  bool lt = x < 0.707106781186547524f;
  float tmp = lt ? x : 0.0f;
  x = x - 1.0f;
  e = e - (lt ? 1.0f : 0.0f);
  x = x + tmp;
  float z  = x * x;
  float x3 = z * x;
  float y  =  7.0376836292e-2f * x + (-1.1514610310e-1f);
  float y1 = -1.2420140846e-1f * x +   1.4249322787e-1f;
  float y2 =  2.0000714765e-1f * x + (-2.4999993993e-1f);
  y  = y  * x +   1.1676998740e-1f;
  y1 = y1 * x + (-1.6668057665e-1f);
  y2 = y2 * x +   3.3333331174e-1f;
  y  = y * x3 + y1;
  y  = y * x3 + y2;
  y  = y * x3;
  y  = y + e * (-2.12194440e-4f);
  x  = x - 0.5f * z;
  x  = x + y;
  x  = x + e * 0.693359375f;
  return x;
}

__device__ __forceinline__ float sumsq_unfused(const float* v) {
  #pragma clang fp contract(off)
  float a = 0.0f;
  #pragma unroll
  for (int d = 0; d < 32; d++) a = a + v[d] * v[d];
  return a;
}

__device__ __forceinline__ void threefry2x32(uint32_t k0, uint32_t k1,
                                             uint32_t x0, uint32_t x1,
                                             uint32_t& o0, uint32_t& o1) {
  uint32_t ks2 = k0 ^ k1 ^ 0x1BD11BDAu;
  x0 += k0; x1 += k1;
#define TF_RND(r) { x0 += x1; x1 = (x1 << (r)) | (x1 >> (32 - (r))); x1 ^= x0; }
  TF_RND(13) TF_RND(15) TF_RND(26) TF_RND(6)
  x0 += k1; x1 += ks2 + 1u;
  TF_RND(17) TF_RND(29) TF_RND(16) TF_RND(24)
  x0 += ks2; x1 += k0 + 2u;
  TF_RND(13) TF_RND(15) TF_RND(26) TF_RND(6)
  x0 += k0; x1 += k1 + 3u;
  TF_RND(17) TF_RND(29) TF_RND(16) TF_RND(24)
  x0 += k1; x1 += ks2 + 4u;
  TF_RND(13) TF_RND(15) TF_RND(26) TF_RND(6)
  x0 += ks2; x1 += k0 + 5u;
#undef TF_RND
  o0 = x0; o1 = x1;
}

// EXACT gumbel (validated R2). Resolve path only.
__device__ __forceinline__ float gumbel_from_bits(uint32_t bits) {
  uint32_t mant = bits >> 9;
  float f = __uint_as_float(0x3F800000u | mant) - 1.0f;
  float u = mant ? f : TINY_F;
  float t = -plog_xla(u);
  return -plog_xla(t);
}

// FAST gumbel via v_log_f32 (scan only; certified by margin).
__device__ __forceinline__ float gumbel_fast(uint32_t bits) {
  uint32_t mant = bits >> 9;
  float f = __uint_as_float(0x3F800000u | mant) - 1.0f;
  float u = mant ? f : TINY_F;
  float t = -(__log2f(u) * LN2F);
  return -(__log2f(t) * LN2F);
}

__device__ __forceinline__ short bf16_rn_bits(float v) {
  __hip_bfloat16 h = __float2bfloat16(v);
  return *reinterpret_cast<short*>(&h);
}
__device__ __forceinline__ float bf16_to_f(short s) {
  __hip_bfloat16 h = *reinterpret_cast<__hip_bfloat16*>(&s);
  return __bfloat162float(h);
}

#define TRACK(P, KL, BEST, SEC, THI, I1, I2)                                   \
  if ((P) > BEST) { THI = SEC; SEC = BEST; I2 = I1; BEST = (P); I1 = (KL); }   \
  else if ((P) > SEC) { THI = SEC; SEC = (P); I2 = (KL); }                     \
  else if ((P) > THI) THI = (P);

// exact phi, reloading x fresh (validated fused ascending chain + plog gumbel)
#define EXACT_PHI_R(OUT, KI)                                                   \
  {                                                                            \
    const int _ki = (KI);                                                      \
    const float* _rp = cbm + (size_t)_ki * DD;                                 \
    float _in = 0.0f;                                                          \
    _Pragma("unroll 1")                                                        \
    for (int _j = 0; _j < 8; _j++) {                                           \
      float4 _q = *(const float4*)(_rp + (_j << 2));                           \
      _in = __builtin_fmaf(xb[(size_t)((_j<<2)+0)*4096 + hw], _q.x, _in);      \
      _in = __builtin_fmaf(xb[(size_t)((_j<<2)+1)*4096 + hw], _q.y, _in);      \
      _in = __builtin_fmaf(xb[(size_t)((_j<<2)+2)*4096 + hw], _q.z, _in);      \
      _in = __builtin_fmaf(xb[(size_t)((_j<<2)+3)*4096 + hw], _q.w, _in);      \
    }                                                                          \
    float _d = (x2e + c2m[_ki]) - 2.0f * _in;                                  \
    float _L = plog_xla(_d);                                                   \
    uint32_t _v0, _v1;                                                         \
    threefry2x32(0u, 42u, 0u, lbase | (uint32_t)_ki, _v0, _v1);                \
    OUT = gumbel_from_bits(_v0 ^ _v1) + _L;                                    \
  }

// prologue: exact c2 table (validated unfused chain) + bf16 hi/lo tables
__global__ __launch_bounds__(256)
void mcq_prep(const float* __restrict__ cb, float* __restrict__ c2tab,
              short* __restrict__ cbh, short* __restrict__ cbl) {
  const int m = blockIdx.x;            // 4
  const int k = threadIdx.x;           // 256
  const float* row = cb + ((size_t)m * KK + k) * DD;
  float cr[DD];
  #pragma unroll
  for (int j = 0; j < 8; j++) {
    float4 q = ((const float4*)row)[j];
    cr[4*j+0] = q.x; cr[4*j+1] = q.y; cr[4*j+2] = q.z; cr[4*j+3] = q.w;
  }
  c2tab[m * KK + k] = sumsq_unfused(cr);
  short* hrow = cbh + ((size_t)m * KK + k) * DD;
  short* lrow = cbl + ((size_t)m * KK + k) * DD;
  #pragma unroll
  for (int d = 0; d < DD; d++) {
    float v = cr[d];
    short hb = bf16_rn_bits(v);
    float hf = bf16_to_f(hb);
    short lb = bf16_rn_bits(v - hf);
    hrow[d] = hb; lrow[d] = lb;
  }
}

__global__ __launch_bounds__(256, 8)
void mcq_mfma(const float* __restrict__ x, const float* __restrict__ cb,
              const float* __restrict__ c2tab, const short* __restrict__ cbh,
              const short* __restrict__ cbl, float* __restrict__ sample,
              float* __restrict__ code, float* __restrict__ logit) {
  __shared__ int s_wb[64];

  const int t   = threadIdx.x;
  const int l   = t & 63, wvw = t >> 6;      // lane, wave
  const int grp = l >> 4;                    // 0..3
  const int pbase = blockIdx.x << 6;         // 4096 blocks x 64 px
  const int nm  = pbase >> 12;               // uniform (64 | 4096)
  const int m   = nm & 3;
  const int pxl = (wvw << 4) + (l & 15);     // 0..63
  const int gp  = pbase + pxl;
  const int hw  = (pbase & 4095) + pxl;

  const float* cbm = cb + (size_t)m * (KK * DD);
  const float* c2m = c2tab + m * KK;
  const short* chm = cbh + (size_t)m * (KK * DD);
  const short* clm = cbl + (size_t)m * (KK * DD);
  const float* xb  = x + (size_t)nm * 131072;

  // B-frag (x) hi/lo + fast x2 (fast path only; exact x2 recomputed on resolve)
  bf16x8 bh, bl;
  float x2p = 0.0f;
  #pragma unroll
  for (int j = 0; j < 8; j++) {
    const int d = (grp << 3) + j;
    float v = xb[(size_t)d * 4096 + hw];
    short hbits = bf16_rn_bits(v);
    float hf = bf16_to_f(hbits);
    short lbits = bf16_rn_bits(v - hf);
    bh[j] = hbits; bl[j] = lbits;
    x2p = __builtin_fmaf(v, v, x2p);
  }
  x2p += __shfl_xor(x2p, 16, 64);
  x2p += __shfl_xor(x2p, 32, 64);
  const float x2f = x2p;

  float* lrowg = logit + ((size_t)gp << 8) + (grp << 2);
  const uint32_t lbase = (uint32_t)gp << 8;

  float best = -__builtin_inff(), sec = -__builtin_inff(), thi = -__builtin_inff();
  int bi1 = 0, bi2 = 0;

  #pragma unroll 1
  for (int kt = 0; kt < 16; kt++) {
    const int krow = (kt << 4) + (l & 15);
    const bf16x8 ah = *(const bf16x8*)(chm + (size_t)krow * DD + (grp << 3));
    const bf16x8 al = *(const bf16x8*)(clm + (size_t)krow * DD + (grp << 3));
    f32x4 acc = {0.0f, 0.0f, 0.0f, 0.0f};
    acc = __builtin_amdgcn_mfma_f32_16x16x32_bf16(al, bh, acc, 0, 0, 0);
    acc = __builtin_amdgcn_mfma_f32_16x16x32_bf16(ah, bl, acc, 0, 0, 0);
    acc = __builtin_amdgcn_mfma_f32_16x16x32_bf16(ah, bh, acc, 0, 0, 0);
    const float4 c2q = *(const float4*)(c2m + (kt << 4) + (grp << 2));
    const int kb = (kt << 4) + (grp << 2);

    float L0, L1, L2, L3;
#define ELEM(R, C2V, LV)                                                       \
    {                                                                          \
      float dist = (x2f + (C2V)) - 2.0f * acc[R];                              \
      LV = __log2f(dist) * LN2F;                                               \
      uint32_t v0_, v1_;                                                       \
      threefry2x32(0u, 42u, 0u, lbase | (uint32_t)(kb + (R)), v0_, v1_);       \
      float p_ = gumbel_fast(v0_ ^ v1_) + LV;                                  \
      const int kk_ = kb + (R);                                                \
      TRACK(p_, kk_, best, sec, thi, bi1, bi2)                                 \
    }
    ELEM(0, c2q.x, L0)
    ELEM(1, c2q.y, L1)
    ELEM(2, c2q.z, L2)
    ELEM(3, c2q.w, L3)
#undef ELEM
    *(float4*)(lrowg + (kt << 4)) = make_float4(L0, L1, L2, L3);
  }

  // merge top-3 across the 4 lanes sharing this px (first-occurrence ties)
#define MERGE(OFF)                                                             \
  {                                                                            \
    float ob = __shfl_xor(best, OFF, 64);                                      \
    float os = __shfl_xor(sec,  OFF, 64);                                      \
    float ot = __shfl_xor(thi,  OFF, 64);                                      \
    int  oi1 = __shfl_xor(bi1,  OFF, 64);                                      \
    int  oi2 = __shfl_xor(bi2,  OFF, 64);                                      \
    bool take = (ob > best) || (ob == best && oi1 < bi1);                      \
    float wb = take ? ob : best, ws2 = take ? os : sec, wt = take ? ot : thi;  \
    int  wi1 = take ? oi1 : bi1, wi2 = take ? oi2 : bi2;                       \
    float lb = take ? best : ob, ls = take ? sec : os;                         \
    int  li1 = take ? bi1 : oi1;                                               \
    bool s2 = (ws2 > lb) || (ws2 == lb && wi2 < li1);                          \
    best = wb; bi1 = wi1;                                                      \
    if (s2) { sec = ws2; bi2 = wi2; thi = fmaxf(wt, lb); }                     \
    else    { sec = lb;  bi2 = li1; thi = fmaxf(ws2, ls); }                    \
  }
  MERGE(16)
  MERGE(32)
#undef MERGE

  if (l < 16) {
    int w;
    if (best - sec > MARGIN) {
      w = bi1;
    } else {
      // exact x2 (validated unfused chain), fresh loads
      float x2e;
      {
        #pragma clang fp contract(off)
        float a = 0.0f;
        #pragma unroll 1
        for (int d = 0; d < DD; d++) {
          float v = xb[(size_t)d * 4096 + hw];
          a = a + v * v;
        }
        x2e = a;
      }
      if (best - thi > MARGIN) {
        int ka = bi1 < bi2 ? bi1 : bi2;
        int kb2 = bi1 < bi2 ? bi2 : bi1;
        float fa, fb;
        EXACT_PHI_R(fa, ka)
        EXACT_PHI_R(fb, kb2)
        w = (fb > fa) ? kb2 : ka;      // tie -> smaller k (first occurrence)
      } else {
        float bb = -__builtin_inff(); int wbb = 0;
        #pragma unroll 1
        for (int k2i = 0; k2i < KK; k2i++) {
          float ph;
          EXACT_PHI_R(ph, k2i)
          if (ph > bb) { bb = ph; wbb = k2i; }
        }
        w = wbb;
      }
    }
    code[gp] = (float)w;
    s_wb[pxl] = w;
  }
  __syncthreads();

  // cooperative one-hot sample: wave wvw writes rows [wvw*16, wvw*16+16)
  const int k0 = l << 2;
  for (int r = wvw * 16; r < wvw * 16 + 16; r++) {
    const int wr = s_wb[r];
    float4 v;
    v.x = (wr == k0 + 0) ? 1.0f : 0.0f;
    v.y = (wr == k0 + 1) ? 1.0f : 0.0f;
    v.z = (wr == k0 + 2) ? 1.0f : 0.0f;
    v.w = (wr == k0 + 3) ? 1.0f : 0.0f;
    ((float4*)(sample + (((size_t)(pbase + r)) << 8)))[l] = v;
  }
}

extern "C" void kernel_launch(void* const* d_in, const int* in_sizes, int n_in,
                              void* d_out, int out_size, void* d_ws, size_t ws_size,
                              hipStream_t stream) {
  const float* x  = (const float*)d_in[0];
  const float* cb = (const float*)d_in[1];

  float* out_f  = (float*)d_out;
  float* sample = out_f;                       // 67108864
  float* code   = out_f + 67108864;            // 262144 (as float)
  float* logit  = out_f + 67108864 + 262144;   // 67108864

  float* c2tab  = (float*)d_ws;                          // 4 KB
  short* cbh    = (short*)((char*)d_ws + 4096);          // 64 KB
  short* cbl    = (short*)((char*)d_ws + 4096 + 65536);  // 64 KB

  mcq_prep<<<4, 256, 0, stream>>>(cb, c2tab, cbh, cbl);
  mcq_mfma<<<4096, 256, 0, stream>>>(x, cb, c2tab, cbh, cbl, sample, code, logit);
}